// Round 5
// baseline (126.091 us; speedup 1.0000x reference)
//
#include <hip/hip_runtime.h>
#include <hip/hip_bf16.h>

#define N_ROWS 4096
#define D_DIM  768
#define MARGIN 1.0f
#define EPS_F  1e-12f
#define BK 32            // K-chunk per LDS stage (32 bf16 = 64 B per row)
#define KITERS (D_DIM / BK)   // 24

typedef __bf16 bf16x8 __attribute__((ext_vector_type(8)));
typedef float  f32x4  __attribute__((ext_vector_type(4)));

// async global->LDS DMA, 16 B per lane; LDS dst = wave-uniform base + lane*16
#define GLD16(gp, lp)                                                          \
    __builtin_amdgcn_global_load_lds(                                         \
        (const __attribute__((address_space(1))) void*)(gp),                  \
        (__attribute__((address_space(3))) void*)(lp), 16, 0, 0)

// ---------------------------------------------------------------------------
// Kernel 1: per-row sum of squares (fp32) + bf16 cast, one wave per row.
// ---------------------------------------------------------------------------
__global__ __launch_bounds__(256) void prep_kernel(const float* __restrict__ emb,
                                                   unsigned short* __restrict__ ebf,
                                                   float* __restrict__ sq) {
    const int wave = threadIdx.x >> 6;
    const int lane = threadIdx.x & 63;
    const int row  = blockIdx.x * 4 + wave;

    const float4* rp = (const float4*)(emb + (size_t)row * D_DIM);   // 192 float4/row
    unsigned short* op = ebf + (size_t)row * D_DIM;

    float s = 0.f;
#pragma unroll
    for (int t = 0; t < 3; ++t) {
        const int idx = lane + t * 64;
        float4 v = rp[idx];
        s += v.x * v.x + v.y * v.y + v.z * v.z + v.w * v.w;
        union { ushort4 u4; __hip_bfloat16 h[4]; } o;
        o.h[0] = __float2bfloat16(v.x);
        o.h[1] = __float2bfloat16(v.y);
        o.h[2] = __float2bfloat16(v.z);
        o.h[3] = __float2bfloat16(v.w);
        *(ushort4*)(op + idx * 4) = o.u4;
    }
    for (int off = 32; off; off >>= 1) s += __shfl_down(s, off, 64);
    if (lane == 0) sq[row] = s;
}

// ---------------------------------------------------------------------------
// Kernel 2: 2 INDEPENDENT waves per 128-thread block, each wave one 64x64
// pair tile, double-buffered BK=32 GLD16 staging, NO __syncthreads in the
// K-loop. Software pipeline: issue prefetch group (8 GLD16) for k+1, then
// s_waitcnt vmcnt(8) -> only iter k's group is drained; k+1 stays in flight.
// XOR-swizzled unpadded LDS (row = 64 B = 4 granules): granule g of row r
// holds global granule g^(r&3); frag reads use granule qd^(ln16&3) ->
// 8 lanes per 4-bank group, conflict-free.
// 1040 blocks -> 2080 tiles (tj>=ti), supertile order for L2 locality.
// Off-diagonal tiles weighted x2; diagonal skips i==j. Scale 1/(N*(N-1)).
// ---------------------------------------------------------------------------
__global__ __launch_bounds__(128, 2) void pair_kernel(const __hip_bfloat16* __restrict__ ebf_,
                                                      const float* __restrict__ sq,
                                                      const int* __restrict__ labels,
                                                      float* __restrict__ out) {
    const int wave = threadIdx.x >> 6;
    const int lane = threadIdx.x & 63;
    const int qd   = lane >> 4;
    const int ln16 = lane & 15;

    // ---- supertile tile decode for t = blockIdx.x*2 + wave ----
    // 16 diag STs x 10 tiles = 160; 120 off-diag STs x 16 tiles = 1920.
    int ti, tj;
    {
        int t = blockIdx.x * 2 + wave;
        if (t < 160) {
            const int s = t / 10;
            int rr = t % 10, di = 0;
            while (rr >= 4 - di) { rr -= 4 - di; ++di; }
            ti = s * 4 + di;
            tj = s * 4 + di + rr;
        } else {
            const int b2 = t - 160;
            int rr = b2 >> 4, si = 0;
            const int w = b2 & 15;
            while (rr >= 15 - si) { rr -= 15 - si; ++si; }
            ti = si * 4 + (w >> 2);
            tj = (si + 1 + rr) * 4 + (w & 3);
        }
    }
    const int i0 = ti * 64, j0 = tj * 64;

    // [wave][buf][A/B][64 rows x 32 cols] = 32 KiB total
    __shared__ __align__(16) unsigned short lds[2][2][2][64 * BK];

    const unsigned short* ebf = (const unsigned short*)ebf_;

    f32x4 acc[4][4];
#pragma unroll
    for (int m = 0; m < 4; ++m)
#pragma unroll
        for (int n = 0; n < 4; ++n) acc[m][n] = (f32x4){0.f, 0.f, 0.f, 0.f};

    // staging map: inst i covers rows [i*16, i*16+16); lane l -> row i*16+(l>>2),
    // LDS granule l&3 holding global granule (l&3)^((l>>2)&3)
    const int sr = lane >> 2;                 // 0..15
    const int sg = (lane & 3) ^ (sr & 3);     // swizzled source granule
    const unsigned short* gA = ebf + (size_t)(i0 + sr) * D_DIM + sg * 8;
    const unsigned short* gB = ebf + (size_t)(j0 + sr) * D_DIM + sg * 8;

#define STAGE(p, k0)                                                           \
    do {                                                                       \
        unsigned short* dA_ = &lds[wave][(p)][0][0];                           \
        unsigned short* dB_ = &lds[wave][(p)][1][0];                           \
        _Pragma("unroll")                                                      \
        for (int i_ = 0; i_ < 4; ++i_) {                                       \
            GLD16(gA + (size_t)i_ * 16 * D_DIM + (k0), dA_ + i_ * 16 * BK);    \
            GLD16(gB + (size_t)i_ * 16 * D_DIM + (k0), dB_ + i_ * 16 * BK);    \
        }                                                                      \
    } while (0)

    STAGE(0, 0);
    asm volatile("s_waitcnt vmcnt(0)" ::: "memory");   // clean baseline count

    const int rg = ln16 & 3;
#pragma unroll 2
    for (int k = 0; k < KITERS; ++k) {
        const int nk = (k + 1 < KITERS) ? (k + 1) * BK : 0;  // wrap: harmless reload
        asm volatile("" ::: "memory");            // keep prior ds_reads above GLDs
        STAGE((k + 1) & 1, nk);                   // prefetch next chunk (8 GLD16)
        asm volatile("s_waitcnt vmcnt(8)" ::: "memory");  // iter-k group drained
        const unsigned short* cA = &lds[wave][k & 1][0][0];
        const unsigned short* cB = &lds[wave][k & 1][1][0];
        bf16x8 af[4], bv[4];
#pragma unroll
        for (int m = 0; m < 4; ++m)
            af[m] = *(const bf16x8*)&cA[(m * 16 + ln16) * BK + (qd ^ rg) * 8];
#pragma unroll
        for (int n = 0; n < 4; ++n)
            bv[n] = *(const bf16x8*)&cB[(n * 16 + ln16) * BK + (qd ^ rg) * 8];
#pragma unroll
        for (int m = 0; m < 4; ++m)
#pragma unroll
            for (int n = 0; n < 4; ++n)
                acc[m][n] = __builtin_amdgcn_mfma_f32_16x16x32_bf16(
                    af[m], bv[n], acc[m][n], 0, 0, 0);
    }
#undef STAGE

    // ---- epilogue: contrastive loss per pair ----
    float psum = 0.f;
#pragma unroll
    for (int m = 0; m < 4; ++m) {
#pragma unroll
        for (int n = 0; n < 4; ++n) {
#pragma unroll
            for (int r = 0; r < 4; ++r) {
                const int gi = i0 + m * 16 + qd * 4 + r;   // C row
                const int gj = j0 + n * 16 + ln16;         // C col
                const float g = acc[m][n][r];
                float d2 = fmaxf(sq[gi] + sq[gj] - 2.0f * g, 0.0f);
                const float dist = sqrtf(d2 + EPS_F);
                const float h = fmaxf(MARGIN - dist, 0.0f);
                const float pl = (labels[gi] == labels[gj]) ? d2 : h * h;
                if (gi != gj) psum += pl;
            }
        }
    }

    for (int off = 32; off; off >>= 1) psum += __shfl_down(psum, off, 64);
    if (lane == 0) {
        const float wgt = (ti == tj) ? 1.0f : 2.0f;
        const float scale = 1.0f / ((float)N_ROWS * (float)(N_ROWS - 1));
        atomicAdd(out, psum * wgt * scale);
    }
}

// ---------------------------------------------------------------------------
extern "C" void kernel_launch(void* const* d_in, const int* in_sizes, int n_in,
                              void* d_out, int out_size, void* d_ws, size_t ws_size,
                              hipStream_t stream) {
    const float* emb  = (const float*)d_in[0];
    const int* labels = (const int*)d_in[1];
    float* out        = (float*)d_out;

    unsigned short* ebf = (unsigned short*)d_ws;
    float* sq = (float*)((char*)d_ws + (size_t)N_ROWS * D_DIM * sizeof(unsigned short));

    hipMemsetAsync(d_out, 0, sizeof(float), stream);
    prep_kernel<<<N_ROWS / 4, 256, 0, stream>>>(emb, ebf, sq);

    pair_kernel<<<1040, 128, 0, stream>>>((const __hip_bfloat16*)ebf, sq, labels, out);
}